// Round 6
// baseline (1106.841 us; speedup 1.0000x reference)
//
#include <hip/hip_runtime.h>
#include <math.h>

#define Bsz 512
#define Tsz 512
#define Hd 64
#define CHX 16            // x staging chunk (time steps)

typedef float v2f __attribute__((ext_vector_type(2)));

__device__ __forceinline__ float fsig(float x){ return 1.0f/(1.0f+__expf(-x)); }
__device__ __forceinline__ float ftanh(float x){
    float ax=fabsf(x); float e=__expf(-2.0f*ax);
    float t=(1.0f-e)/(1.0f+e); return copysignf(t,x);
}
__device__ __forceinline__ float rlane(float v, int k){
    return __int_as_float(__builtin_amdgcn_readlane(__float_as_int(v), k));
}

// 4 waves per batch row, gate-split producer/consumer, 1 barrier per step.
//  wave u=0,1 (producers): gates {2u,2u+1}. x kept in regs, transposed layout
//    (lane 4t+m holds x[t][4r+m]) so per-step broadcast = v_readlane with
//    dynamic-uniform lane (no LDS datapath, no dynamic reg indexing).
//    Writes x-part pregates (+bias) to parity ring. 16-step staging, 1 ahead.
//  wave u=0,1 (consumers, wv=2+u): gates {2u,2u+1} Whh in regs (128 floats).
//    Pipelined: at interval s finish step s-2 (own pregates in regs + other
//    pair via parity xch), update c,h redundantly, readlane-broadcast h,
//    matvec for step s-1, write xch. All cross-wave data crosses a barrier.
template<int K, bool STORE_H, bool DO_FC>
__global__ __launch_bounds__(256, 2)
void lstm_layer(const float* __restrict__ xin,    // [B, T, K]
                const float4* __restrict__ Wih4,  // [256, K/4]
                const float4* __restrict__ Whh4,  // [256, 16]
                const float* __restrict__ bih, const float* __restrict__ bhh,
                float* __restrict__ hout,         // [B, T, 64] if STORE_H
                const float* __restrict__ fcW, const float* __restrict__ fcb,
                float* __restrict__ out)          // [B] if DO_FC
{
    __shared__ float2 ring[2][2][64];   // [parity][u][lane] = x-part pregate pair
    __shared__ float2 xch [2][2][64];   // [parity][u][lane] = full pregate pair

    const int lane = threadIdx.x & 63;
    const int wv   = threadIdx.x >> 6;
    const int b    = blockIdx.x;
    constexpr int KQ  = K / 4;          // float4 per row / xregs per lane
    constexpr int NCH = Tsz / CHX;

    if (wv < 2) {
        // ================= producer =================
        const int u  = wv;
        const int rA = (2*u) * 64 + lane;
        const int rB = (2*u+1) * 64 + lane;
        float4 wA[KQ], wB[KQ];
        #pragma unroll
        for (int q = 0; q < KQ; ++q) wA[q] = Wih4[rA * KQ + q];
        #pragma unroll
        for (int q = 0; q < KQ; ++q) wB[q] = Wih4[rB * KQ + q];
        const float bA = bih[rA] + bhh[rA];
        const float bB = bih[rB] + bhh[rB];

        const float* xb = xin + (size_t)b * Tsz * K;
        const int t0 = lane >> 2, m = lane & 3;      // lane 4t+m <-> x[t][4r+m]
        float xcur[KQ], xnxt[KQ];
        #pragma unroll
        for (int r = 0; r < KQ; ++r) xcur[r] = xb[(0*CHX + t0) * K + 4*r + m];
        #pragma unroll
        for (int r = 0; r < KQ; ++r) xnxt[r] = xb[(1*CHX + t0) * K + 4*r + m];

        #pragma unroll 1
        for (int s = 0; s < Tsz + 2; ++s) {
            if (s < Tsz) {
                const int j = s & (CHX - 1);
                if (j == 0 && s > 0) {
                    #pragma unroll
                    for (int r = 0; r < KQ; ++r) xcur[r] = xnxt[r];
                    const int c2 = (s >> 4) + 1;
                    if (c2 < NCH) {
                        #pragma unroll
                        for (int r = 0; r < KQ; ++r)
                            xnxt[r] = xb[(c2*CHX + t0) * K + 4*r + m];
                    }
                }
                const int lb = j * 4;                // dynamic-uniform lane base
                v2f aA0 = {bA, 0.f}, aA1 = {0.f, 0.f};
                v2f aB0 = {bB, 0.f}, aB1 = {0.f, 0.f};
                #pragma unroll
                for (int q = 0; q < KQ; ++q) {
                    float x0 = rlane(xcur[q], lb + 0);
                    float x1 = rlane(xcur[q], lb + 1);
                    float x2 = rlane(xcur[q], lb + 2);
                    float x3 = rlane(xcur[q], lb + 3);
                    v2f x01 = {x0, x1}, x23 = {x2, x3};
                    aA0 = __builtin_elementwise_fma(x01, v2f{wA[q].x, wA[q].y}, aA0);
                    aA1 = __builtin_elementwise_fma(x23, v2f{wA[q].z, wA[q].w}, aA1);
                    aB0 = __builtin_elementwise_fma(x01, v2f{wB[q].x, wB[q].y}, aB0);
                    aB1 = __builtin_elementwise_fma(x23, v2f{wB[q].z, wB[q].w}, aB1);
                }
                float pA = (aA0.x + aA0.y) + (aA1.x + aA1.y);
                float pB = (aB0.x + aB0.y) + (aB1.x + aB1.y);
                ring[s & 1][u][lane] = float2{pA, pB};
            }
            __syncthreads();
        }
    } else {
        // ================= consumer =================
        const int u  = wv - 2;
        const int rA = (2*u) * 64 + lane;
        const int rB = (2*u+1) * 64 + lane;
        float4 whA[16], whB[16];
        #pragma unroll
        for (int q = 0; q < 16; ++q) whA[q] = Whh4[rA * 16 + q];
        #pragma unroll
        for (int q = 0; q < 16; ++q) whB[q] = Whh4[rB * 16 + q];

        float hs[64];
        #pragma unroll
        for (int k = 0; k < 64; ++k) hs[k] = 0.0f;
        float cc = 0.f, hl = 0.f;
        float2 pm = {0.f, 0.f};
        float* hrow = STORE_H ? (hout + (size_t)b * Tsz * Hd) : nullptr;

        #pragma unroll 1
        for (int s = 0; s < Tsz + 2; ++s) {
            if (s >= 2) {
                float2 oth = xch[(s - 1) & 1][1 - u][lane];
                float pi, pf, pg, po;
                if (u == 0) { pi = pm.x; pf = pm.y; pg = oth.x; po = oth.y; }
                else        { pg = pm.x; po = pm.y; pi = oth.x; pf = oth.y; }
                float gi = fsig(pi), gf = fsig(pf), gg = ftanh(pg), go = fsig(po);
                cc = gf * cc + gi * gg;
                hl = go * ftanh(cc);
                if (STORE_H && u == 0) hrow[(s - 2) * Hd + lane] = hl;
                #pragma unroll
                for (int k = 0; k < 64; ++k) hs[k] = rlane(hl, k);
            }
            if (s >= 1 && s <= Tsz) {
                float2 rg = ring[(s - 1) & 1][u][lane];
                v2f aA0 = {0.f, 0.f}, aA1 = {0.f, 0.f};
                v2f aB0 = {0.f, 0.f}, aB1 = {0.f, 0.f};
                #pragma unroll
                for (int q = 0; q < 16; ++q) {
                    v2f h01 = {hs[4*q + 0], hs[4*q + 1]};
                    v2f h23 = {hs[4*q + 2], hs[4*q + 3]};
                    aA0 = __builtin_elementwise_fma(h01, v2f{whA[q].x, whA[q].y}, aA0);
                    aA1 = __builtin_elementwise_fma(h23, v2f{whA[q].z, whA[q].w}, aA1);
                    aB0 = __builtin_elementwise_fma(h01, v2f{whB[q].x, whB[q].y}, aB0);
                    aB1 = __builtin_elementwise_fma(h23, v2f{whB[q].z, whB[q].w}, aB1);
                }
                pm.x = rg.x + (aA0.x + aA0.y) + (aA1.x + aA1.y);
                pm.y = rg.y + (aB0.x + aB0.y) + (aB1.x + aB1.y);
                xch[s & 1][u][lane] = pm;
            }
            __syncthreads();
        }

        if (DO_FC && u == 0) {
            float p = hl * fcW[lane];
            #pragma unroll
            for (int off = 32; off > 0; off >>= 1) p += __shfl_down(p, off);
            if (lane == 0) out[b] = p + fcb[0];
        }
    }
}

extern "C" void kernel_launch(void* const* d_in, const int* in_sizes, int n_in,
                              void* d_out, int out_size, void* d_ws, size_t ws_size,
                              hipStream_t stream)
{
    const float* x    = (const float*)d_in[0];
    const float* Wih0 = (const float*)d_in[1];
    const float* Whh0 = (const float*)d_in[2];
    const float* bih0 = (const float*)d_in[3];
    const float* bhh0 = (const float*)d_in[4];
    const float* Wih1 = (const float*)d_in[5];
    const float* Whh1 = (const float*)d_in[6];
    const float* bih1 = (const float*)d_in[7];
    const float* bhh1 = (const float*)d_in[8];
    const float* fcW  = (const float*)d_in[9];
    const float* fcb  = (const float*)d_in[10];
    float* out = (float*)d_out;
    float* h1  = (float*)d_ws;   // B*T*H fp32 = 64 MB scratch

    lstm_layer<32, true,  false><<<dim3(Bsz), dim3(256), 0, stream>>>(
        x, (const float4*)Wih0, (const float4*)Whh0, bih0, bhh0, h1,
        nullptr, nullptr, nullptr);
    lstm_layer<64, false, true ><<<dim3(Bsz), dim3(256), 0, stream>>>(
        h1, (const float4*)Wih1, (const float4*)Whh1, bih1, bhh1, nullptr,
        fcW, fcb, out);
}

// Round 7
// 1099.445 us; speedup vs baseline: 1.0067x; 1.0067x over previous
//
#include <hip/hip_runtime.h>
#include <math.h>

#define Bsz 512
#define Tsz 512
#define Hd 64
#define CHX 16            // x staging chunk (time steps)

typedef float v2f __attribute__((ext_vector_type(2)));

__device__ __forceinline__ float fsig(float x){ return 1.0f/(1.0f+__expf(-x)); }
__device__ __forceinline__ float ftanh(float x){
    float ax=fabsf(x); float e=__expf(-2.0f*ax);
    float t=(1.0f-e)/(1.0f+e); return copysignf(t,x);
}
__device__ __forceinline__ float rlane(float v, int k){
    return __int_as_float(__builtin_amdgcn_readlane(__float_as_int(v), k));
}

// LDS-only barrier: s_waitcnt lgkmcnt(0) + s_barrier, WITHOUT the vmcnt(0)
// drain __syncthreads inserts. Global prefetch loads stay in flight across
// steps; LDS ring/xch ordering is fully covered by the local fences.
__device__ __forceinline__ void lds_barrier(){
    __builtin_amdgcn_fence(__ATOMIC_SEQ_CST, "workgroup", "local");
    __builtin_amdgcn_s_barrier();
    __builtin_amdgcn_fence(__ATOMIC_SEQ_CST, "workgroup", "local");
}

// 4 waves per batch row, gate-split producer/consumer, 1 LDS-barrier per step.
//  wave u=0,1 (producers): gates {2u,2u+1}. x kept in regs, transposed layout
//    (lane 4t+m holds x[t][4r+m]) so per-step broadcast = v_readlane with
//    dynamic-uniform lane (no LDS datapath, no dynamic reg indexing).
//    Writes x-part pregates (+bias) to parity ring. 16-step staging, 1 ahead.
//  wave u=0,1 (consumers, wv=2+u): gates {2u,2u+1} Whh in regs (128 floats).
//    Pipelined: at interval s finish step s-2 (own pregates in regs + other
//    pair via parity xch), update c,h redundantly, readlane-broadcast h,
//    matvec for step s-1, write xch. All cross-wave data crosses a barrier.
// __launch_bounds__(256,1): min-waves=1 keeps the allocator from parking the
// weight arrays in AGPRs (r1/r6 showed (.,2) -> VGPR 76/96 + accvgpr tax;
// r3/r5 showed (.,1) -> full arch-VGPR allocation).
template<int K, bool STORE_H, bool DO_FC>
__global__ __launch_bounds__(256, 1)
void lstm_layer(const float* __restrict__ xin,    // [B, T, K]
                const float4* __restrict__ Wih4,  // [256, K/4]
                const float4* __restrict__ Whh4,  // [256, 16]
                const float* __restrict__ bih, const float* __restrict__ bhh,
                float* __restrict__ hout,         // [B, T, 64] if STORE_H
                const float* __restrict__ fcW, const float* __restrict__ fcb,
                float* __restrict__ out)          // [B] if DO_FC
{
    __shared__ float2 ring[2][2][64];   // [parity][u][lane] = x-part pregate pair
    __shared__ float2 xch [2][2][64];   // [parity][u][lane] = full pregate pair

    const int lane = threadIdx.x & 63;
    const int wv   = threadIdx.x >> 6;
    const int b    = blockIdx.x;
    constexpr int KQ  = K / 4;          // float4 per row / xregs per lane
    constexpr int NCH = Tsz / CHX;

    if (wv < 2) {
        // ================= producer =================
        const int u  = wv;
        const int rA = (2*u) * 64 + lane;
        const int rB = (2*u+1) * 64 + lane;
        float4 wA[KQ], wB[KQ];
        #pragma unroll
        for (int q = 0; q < KQ; ++q) wA[q] = Wih4[rA * KQ + q];
        #pragma unroll
        for (int q = 0; q < KQ; ++q) wB[q] = Wih4[rB * KQ + q];
        const float bA = bih[rA] + bhh[rA];
        const float bB = bih[rB] + bhh[rB];

        const float* xb = xin + (size_t)b * Tsz * K;
        const int t0 = lane >> 2, m = lane & 3;      // lane 4t+m <-> x[t][4r+m]
        float xcur[KQ], xnxt[KQ];
        #pragma unroll
        for (int r = 0; r < KQ; ++r) xcur[r] = xb[(0*CHX + t0) * K + 4*r + m];
        #pragma unroll
        for (int r = 0; r < KQ; ++r) xnxt[r] = xb[(1*CHX + t0) * K + 4*r + m];

        #pragma unroll 1
        for (int s = 0; s < Tsz + 2; ++s) {
            if (s < Tsz) {
                const int j = s & (CHX - 1);
                if (j == 0 && s > 0) {
                    #pragma unroll
                    for (int r = 0; r < KQ; ++r) xcur[r] = xnxt[r];
                    const int c2 = (s >> 4) + 1;
                    if (c2 < NCH) {
                        #pragma unroll
                        for (int r = 0; r < KQ; ++r)
                            xnxt[r] = xb[(c2*CHX + t0) * K + 4*r + m];
                    }
                }
                const int lb = j * 4;                // dynamic-uniform lane base
                v2f aA0 = {bA, 0.f}, aA1 = {0.f, 0.f};
                v2f aB0 = {bB, 0.f}, aB1 = {0.f, 0.f};
                #pragma unroll
                for (int q = 0; q < KQ; ++q) {
                    float x0 = rlane(xcur[q], lb + 0);
                    float x1 = rlane(xcur[q], lb + 1);
                    float x2 = rlane(xcur[q], lb + 2);
                    float x3 = rlane(xcur[q], lb + 3);
                    v2f x01 = {x0, x1}, x23 = {x2, x3};
                    aA0 = __builtin_elementwise_fma(x01, v2f{wA[q].x, wA[q].y}, aA0);
                    aA1 = __builtin_elementwise_fma(x23, v2f{wA[q].z, wA[q].w}, aA1);
                    aB0 = __builtin_elementwise_fma(x01, v2f{wB[q].x, wB[q].y}, aB0);
                    aB1 = __builtin_elementwise_fma(x23, v2f{wB[q].z, wB[q].w}, aB1);
                }
                float pA = (aA0.x + aA0.y) + (aA1.x + aA1.y);
                float pB = (aB0.x + aB0.y) + (aB1.x + aB1.y);
                ring[s & 1][u][lane] = float2{pA, pB};
            }
            lds_barrier();
        }
    } else {
        // ================= consumer =================
        const int u  = wv - 2;
        const int rA = (2*u) * 64 + lane;
        const int rB = (2*u+1) * 64 + lane;
        float4 whA[16], whB[16];
        #pragma unroll
        for (int q = 0; q < 16; ++q) whA[q] = Whh4[rA * 16 + q];
        #pragma unroll
        for (int q = 0; q < 16; ++q) whB[q] = Whh4[rB * 16 + q];

        float hs[64];
        #pragma unroll
        for (int k = 0; k < 64; ++k) hs[k] = 0.0f;
        float cc = 0.f, hl = 0.f;
        float2 pm = {0.f, 0.f};
        float* hrow = STORE_H ? (hout + (size_t)b * Tsz * Hd) : nullptr;

        #pragma unroll 1
        for (int s = 0; s < Tsz + 2; ++s) {
            if (s >= 2) {
                float2 oth = xch[(s - 1) & 1][1 - u][lane];
                float pi, pf, pg, po;
                if (u == 0) { pi = pm.x; pf = pm.y; pg = oth.x; po = oth.y; }
                else        { pg = pm.x; po = pm.y; pi = oth.x; pf = oth.y; }
                float gi = fsig(pi), gf = fsig(pf), gg = ftanh(pg), go = fsig(po);
                cc = gf * cc + gi * gg;
                hl = go * ftanh(cc);
                if (STORE_H && u == 0) hrow[(s - 2) * Hd + lane] = hl;
                #pragma unroll
                for (int k = 0; k < 64; ++k) hs[k] = rlane(hl, k);
            }
            if (s >= 1 && s <= Tsz) {
                float2 rg = ring[(s - 1) & 1][u][lane];
                v2f aA0 = {0.f, 0.f}, aA1 = {0.f, 0.f};
                v2f aB0 = {0.f, 0.f}, aB1 = {0.f, 0.f};
                #pragma unroll
                for (int q = 0; q < 16; ++q) {
                    v2f h01 = {hs[4*q + 0], hs[4*q + 1]};
                    v2f h23 = {hs[4*q + 2], hs[4*q + 3]};
                    aA0 = __builtin_elementwise_fma(h01, v2f{whA[q].x, whA[q].y}, aA0);
                    aA1 = __builtin_elementwise_fma(h23, v2f{whA[q].z, whA[q].w}, aA1);
                    aB0 = __builtin_elementwise_fma(h01, v2f{whB[q].x, whB[q].y}, aB0);
                    aB1 = __builtin_elementwise_fma(h23, v2f{whB[q].z, whB[q].w}, aB1);
                }
                pm.x = rg.x + (aA0.x + aA0.y) + (aA1.x + aA1.y);
                pm.y = rg.y + (aB0.x + aB0.y) + (aB1.x + aB1.y);
                xch[s & 1][u][lane] = pm;
            }
            lds_barrier();
        }

        if (DO_FC && u == 0) {
            float p = hl * fcW[lane];
            #pragma unroll
            for (int off = 32; off > 0; off >>= 1) p += __shfl_down(p, off);
            if (lane == 0) out[b] = p + fcb[0];
        }
    }
}

extern "C" void kernel_launch(void* const* d_in, const int* in_sizes, int n_in,
                              void* d_out, int out_size, void* d_ws, size_t ws_size,
                              hipStream_t stream)
{
    const float* x    = (const float*)d_in[0];
    const float* Wih0 = (const float*)d_in[1];
    const float* Whh0 = (const float*)d_in[2];
    const float* bih0 = (const float*)d_in[3];
    const float* bhh0 = (const float*)d_in[4];
    const float* Wih1 = (const float*)d_in[5];
    const float* Whh1 = (const float*)d_in[6];
    const float* bih1 = (const float*)d_in[7];
    const float* bhh1 = (const float*)d_in[8];
    const float* fcW  = (const float*)d_in[9];
    const float* fcb  = (const float*)d_in[10];
    float* out = (float*)d_out;
    float* h1  = (float*)d_ws;   // B*T*H fp32 = 64 MB scratch

    lstm_layer<32, true,  false><<<dim3(Bsz), dim3(256), 0, stream>>>(
        x, (const float4*)Wih0, (const float4*)Whh0, bih0, bhh0, h1,
        nullptr, nullptr, nullptr);
    lstm_layer<64, false, true ><<<dim3(Bsz), dim3(256), 0, stream>>>(
        h1, (const float4*)Wih1, (const float4*)Whh1, bih1, bhh1, nullptr,
        fcW, fcb, out);
}